// Round 4
// baseline (609.869 us; speedup 1.0000x reference)
//
#include <hip/hip_runtime.h>
#include <stdint.h>

// Problem constants (B, T, V, E, U)
constexpr int NB = 1024;
constexpr int NT = 80;
constexpr int NV = 50000;
constexpr int NE = 512;
constexpr int NU = 512;

typedef __attribute__((ext_vector_type(8))) __bf16 bf16x8;
typedef __attribute__((ext_vector_type(4))) float f32x4;
typedef __attribute__((ext_vector_type(4))) uint16_t u16x4;
typedef __attribute__((ext_vector_type(4))) float float4v;
typedef __attribute__((ext_vector_type(4))) uint32_t u32x4;

__device__ __forceinline__ uint16_t f2bf(float f) {
  uint32_t u = __builtin_bit_cast(uint32_t, f);
  u += 0x7FFFu + ((u >> 16) & 1u);   // round-to-nearest-even
  return (uint16_t)(u >> 16);
}
__device__ __forceinline__ float bf2f(uint16_t h) {
  uint32_t u = ((uint32_t)h) << 16;
  return __builtin_bit_cast(float, u);
}
__device__ __forceinline__ float tanh_fast(float x) {
  float e = __expf(2.0f * x);
  return 1.0f - 2.0f / (e + 1.0f);
}

// ---------------- prep kernels ----------------

__global__ __launch_bounds__(256) void emb_to_bf16(const float* __restrict__ in,
                                                   uint16_t* __restrict__ out) {
  int i = blockIdx.x * 256 + threadIdx.x;           // 6,400,000 float4s
  float4v v = ((const float4v*)in)[i];
  u16x4 o;
  o.x = f2bf(v.x); o.y = f2bf(v.y); o.z = f2bf(v.z); o.w = f2bf(v.w);
  ((u16x4*)out)[i] = o;
}

// Pack a [K=512][N=512] fp32 weight into MFMA-B-fragment order:
// pack[nt][ks][lane][j] = bf16( W[ks*32 + (lane>>4)*8 + j][nt*16 + (lane&15)] )
__global__ __launch_bounds__(256) void pack_w(const float* __restrict__ w,
                                              uint16_t* __restrict__ out) {
  int idx = blockIdx.x * 256 + threadIdx.x;  // 0..32767 = 32 nt * 16 ks * 64 lanes
  int lane = idx & 63;
  int ks = (idx >> 6) & 15;
  int nt = idx >> 10;
  int n  = nt * 16 + (lane & 15);
  int k0 = ks * 32 + (lane >> 4) * 8;
  uint16_t v[8];
#pragma unroll
  for (int j = 0; j < 8; j++) v[j] = f2bf(w[(size_t)(k0 + j) * NU + n]);
  u16x4* o = (u16x4*)(out + (size_t)idx * 8);
  o[0] = (u16x4){v[0], v[1], v[2], v[3]};
  o[1] = (u16x4){v[4], v[5], v[6], v[7]};
}

// ---------------- projection GEMM ----------------
// Row order t-major: flat row gm = t*NB + b; block = 64 rows of one t.
// Output tiles in MFMA C-fragment order (tile = 256 u16, elem at lane*4+r).
// Depth-4 software pipeline on the A-gather (L3 latency ~600 cyc; 4 stages
// x ~155 cyc of MFMA per ks covers it). Stage index folds under unroll 4.
__global__ __launch_bounds__(256, 2) void proj_gemm(const int* __restrict__ tokens,
                                                    const uint16_t* __restrict__ embb,
                                                    const uint16_t* __restrict__ kpack,
                                                    const float* __restrict__ bias,
                                                    uint16_t* __restrict__ xkp) {
  int wave = threadIdx.x >> 6;
  int lane = threadIdx.x & 63;
  int ln15 = lane & 15;
  int quad = lane >> 4;
  int m0 = blockIdx.x * 64;      // 1280 blocks: 80 t x 16 b-groups
  int t = m0 >> 10;
  int b0 = m0 & 1023;

  int tok[4];
#pragma unroll
  for (int mt = 0; mt < 4; mt++)
    tok[mt] = tokens[(size_t)(b0 + mt * 16 + ln15) * NT + t];

  float bv[8];
#pragma unroll
  for (int nt = 0; nt < 8; nt++) bv[nt] = bias[wave * 128 + nt * 16 + ln15];

  f32x4 acc[4][8];
#pragma unroll
  for (int mt = 0; mt < 4; mt++)
#pragma unroll
    for (int nt = 0; nt < 8; nt++) acc[mt][nt] = (f32x4){0.f, 0.f, 0.f, 0.f};

  // 4-stage A pipeline: aP[s][mt] holds ks' = (ks & ~3) + s appropriately
  bf16x8 aP[4][4];
#pragma unroll
  for (int s = 0; s < 4; s++)
#pragma unroll
    for (int mt = 0; mt < 4; mt++)
      aP[s][mt] = *(const bf16x8*)(embb + (size_t)tok[mt] * NE + s * 32 + quad * 8);

#pragma unroll 4
  for (int ks = 0; ks < 12; ks++) {
    int st = ks & 3;
#pragma unroll
    for (int nt = 0; nt < 8; nt++) {
      int ntg = wave * 8 + nt;
      bf16x8 bfr = *(const bf16x8*)(kpack + (((size_t)ntg * 16 + ks) * 64 + lane) * 8);
#pragma unroll
      for (int mt = 0; mt < 4; mt++)
        acc[mt][nt] = __builtin_amdgcn_mfma_f32_16x16x32_bf16(aP[st][mt], bfr, acc[mt][nt], 0, 0, 0);
    }
    // refill this stage with ks+4
#pragma unroll
    for (int mt = 0; mt < 4; mt++)
      aP[st][mt] = *(const bf16x8*)(embb + (size_t)tok[mt] * NE + (ks + 4) * 32 + quad * 8);
  }
  // tail: ks 12..15, no refill
#pragma unroll
  for (int ks = 12; ks < 16; ks++) {
    int st = ks & 3;
#pragma unroll
    for (int nt = 0; nt < 8; nt++) {
      int ntg = wave * 8 + nt;
      bf16x8 bfr = *(const bf16x8*)(kpack + (((size_t)ntg * 16 + ks) * 64 + lane) * 8);
#pragma unroll
      for (int mt = 0; mt < 4; mt++)
        acc[mt][nt] = __builtin_amdgcn_mfma_f32_16x16x32_bf16(aP[st][mt], bfr, acc[mt][nt], 0, 0, 0);
    }
  }

  // epilogue: C-fragment-order tiles, coalesced 8B/lane stores
#pragma unroll
  for (int mt = 0; mt < 4; mt++) {
    int g = (b0 >> 4) + mt;
#pragma unroll
    for (int nt = 0; nt < 8; nt++) {
      int ntg = wave * 8 + nt;
      size_t tile = ((size_t)t * 64 + g) * 32 + ntg;
      u16x4 o;
      o.x = f2bf(acc[mt][nt][0] + bv[nt]);
      o.y = f2bf(acc[mt][nt][1] + bv[nt]);
      o.z = f2bf(acc[mt][nt][2] + bv[nt]);
      o.w = f2bf(acc[mt][nt][3] + bv[nt]);
      *(u16x4*)(xkp + tile * 256 + (size_t)lane * 4) = o;
    }
  }
}

// ---------------- recurrence ----------------
// 64 blocks x 512 threads. Block g owns rows g*16..+15, all 512 cols.
// Wave w owns n-tiles w*4..+3. R tiering: ks0..11 VGPR-resident, PINNED via
// opaque asm (prevents LLVM rematerializing the loop-invariant global loads
// -- the round-2/3 failure mode that left VGPR_Count at 128); ks12 in LDS;
// ks13..15 streamed from L2 per step. hA double-buffered; one raw s_barrier
// per step with lgkmcnt-only drain (global prefetches stay in flight).
__global__ __launch_bounds__(512, 2)
void rnn_rec(const uint16_t* __restrict__ xkp,
             const uint16_t* __restrict__ rpack,
             const float* __restrict__ fcw,
             const float* __restrict__ fcb,
             float* __restrict__ out) {
  __shared__ uint16_t hA[2][64 * 16 * 8];     // 2 x 16 KB: [buf][chunk][row][8]
  __shared__ uint16_t blB[8 * 4 * 64 * 8];    // 32 KB: ks==12 frags [wave][nt][lane][8]

  int g = blockIdx.x;
  int wave = threadIdx.x >> 6;
  int lane = threadIdx.x & 63;
  int ln15 = lane & 15;
  int quad = lane >> 4;
  int nt0 = wave * 4;

  // resident B-frags ks0..11 (192 VGPR), loaded once and PINNED
  u32x4 bf[4][12];
#pragma unroll
  for (int nt = 0; nt < 4; nt++)
#pragma unroll
    for (int ks = 0; ks < 12; ks++) {
      bf[nt][ks] = *(const u32x4*)(rpack + (((size_t)(nt0 + nt) * 16 + ks) * 64 + lane) * 8);
      asm volatile("" : "+v"(bf[nt][ks]));   // opaque: no remat, must stay in VGPRs
    }

  // ks==12 slice into LDS
#pragma unroll
  for (int nt = 0; nt < 4; nt++)
    *(u32x4*)(blB + (((size_t)wave * 4 + nt) * 64 + lane) * 8) =
        *(const u32x4*)(rpack + (((size_t)(nt0 + nt) * 16 + 12) * 64 + lane) * 8);

  // zero h0 in buffer 0
  {
    u32x4 z = (u32x4){0u, 0u, 0u, 0u};
    ((u32x4*)hA[0])[threadIdx.x * 2] = z;
    ((u32x4*)hA[0])[threadIdx.x * 2 + 1] = z;
  }
  __syncthreads();

  for (int t = 0; t < NT; t++) {
    const uint16_t* hc = hA[t & 1];
    uint16_t* hn = hA[(t + 1) & 1];

    // xk tiles for this step (consumed after the MFMA chain)
    const uint16_t* xb = xkp + (((size_t)t * 64 + g) * 32) * 256;
    u16x4 xv[4];
#pragma unroll
    for (int nt = 0; nt < 4; nt++)
      xv[nt] = *(const u16x4*)(xb + ((size_t)(nt0 + nt)) * 256 + (size_t)lane * 4);

    // stream ks13,14 B-frags (issued now, consumed after the 12 reg slices)
    bf16x8 g13[4], g14[4];
#pragma unroll
    for (int nt = 0; nt < 4; nt++) {
      g13[nt] = *(const bf16x8*)(rpack + (((size_t)(nt0 + nt) * 16 + 13) * 64 + lane) * 8);
      g14[nt] = *(const bf16x8*)(rpack + (((size_t)(nt0 + nt) * 16 + 14) * 64 + lane) * 8);
    }

    f32x4 acc[4];
#pragma unroll
    for (int nt = 0; nt < 4; nt++) acc[nt] = (f32x4){0.f, 0.f, 0.f, 0.f};

    // ks0..11 from pinned registers
#pragma unroll
    for (int ks = 0; ks < 12; ks++) {
      bf16x8 a = *(const bf16x8*)(hc + (((size_t)ks * 4 + quad) * 16 + ln15) * 8);
#pragma unroll
      for (int nt = 0; nt < 4; nt++)
        acc[nt] = __builtin_amdgcn_mfma_f32_16x16x32_bf16(
            a, __builtin_bit_cast(bf16x8, bf[nt][ks]), acc[nt], 0, 0, 0);
    }
    // ks12 from LDS
    {
      bf16x8 a = *(const bf16x8*)(hc + (((size_t)12 * 4 + quad) * 16 + ln15) * 8);
#pragma unroll
      for (int nt = 0; nt < 4; nt++) {
        bf16x8 b = *(const bf16x8*)(blB + (((size_t)wave * 4 + nt) * 64 + lane) * 8);
        acc[nt] = __builtin_amdgcn_mfma_f32_16x16x32_bf16(a, b, acc[nt], 0, 0, 0);
      }
    }
    // ks13,14 streamed
    {
      bf16x8 a = *(const bf16x8*)(hc + (((size_t)13 * 4 + quad) * 16 + ln15) * 8);
#pragma unroll
      for (int nt = 0; nt < 4; nt++)
        acc[nt] = __builtin_amdgcn_mfma_f32_16x16x32_bf16(a, g13[nt], acc[nt], 0, 0, 0);
    }
    {
      bf16x8 a = *(const bf16x8*)(hc + (((size_t)14 * 4 + quad) * 16 + ln15) * 8);
#pragma unroll
      for (int nt = 0; nt < 4; nt++)
        acc[nt] = __builtin_amdgcn_mfma_f32_16x16x32_bf16(a, g14[nt], acc[nt], 0, 0, 0);
    }
    // ks15 streamed late
    {
      bf16x8 g15[4];
#pragma unroll
      for (int nt = 0; nt < 4; nt++)
        g15[nt] = *(const bf16x8*)(rpack + (((size_t)(nt0 + nt) * 16 + 15) * 64 + lane) * 8);
      bf16x8 a = *(const bf16x8*)(hc + (((size_t)15 * 4 + quad) * 16 + ln15) * 8);
#pragma unroll
      for (int nt = 0; nt < 4; nt++)
        acc[nt] = __builtin_amdgcn_mfma_f32_16x16x32_bf16(a, g15[nt], acc[nt], 0, 0, 0);
    }

    // tanh + write h(t+1) into the other buffer
#pragma unroll
    for (int nt = 0; nt < 4; nt++) {
      int cb = (nt0 + nt) * 2 + (ln15 >> 3);   // chunk index of this col
      int j = ln15 & 7;
#pragma unroll
      for (int r = 0; r < 4; r++) {
        float h = tanh_fast(acc[nt][r] + bf2f(xv[nt][r]));
        hn[((size_t)cb * 16 + quad * 4 + r) * 8 + j] = f2bf(h);
      }
    }

    // LDS-only drain + raw barrier: vmcnt loads stay in flight
    asm volatile("s_waitcnt lgkmcnt(0)\n\ts_barrier" ::: "memory");
  }

  // final FC + sigmoid: wave w handles rows 2w, 2w+1 (h_final in buffer 0)
#pragma unroll
  for (int rr = 0; rr < 2; rr++) {
    int row = wave * 2 + rr;
    const uint16_t* hr = hA[0] + ((size_t)lane * 16 + row) * 8;  // chunk=lane
    float p = 0.f;
#pragma unroll
    for (int j = 0; j < 8; j++) p += bf2f(hr[j]) * fcw[lane * 8 + j];
#pragma unroll
    for (int off = 32; off; off >>= 1) p += __shfl_down(p, off);
    if (lane == 0) {
      float logit = p + fcb[0];
      out[g * 16 + row] = 1.0f / (1.0f + __expf(-logit));
    }
  }
}

// ---------------- launcher ----------------
extern "C" void kernel_launch(void* const* d_in, const int* in_sizes, int n_in,
                              void* d_out, int out_size, void* d_ws, size_t ws_size,
                              hipStream_t stream) {
  const int* tokens   = (const int*)d_in[0];
  const float* emb    = (const float*)d_in[1];
  const float* kernel_w = (const float*)d_in[2];
  const float* rec_w  = (const float*)d_in[3];
  const float* bias   = (const float*)d_in[4];
  const float* fcw    = (const float*)d_in[5];
  const float* fcb    = (const float*)d_in[6];
  float* out = (float*)d_out;

  // workspace: emb_bf16 51.2MB | kpack 0.5MB | rpack 0.5MB | xkp 83.9MB
  uint16_t* embb  = (uint16_t*)d_ws;
  uint16_t* kpack = embb + (size_t)NV * NE;
  uint16_t* rpack = kpack + (size_t)NE * NU;
  uint16_t* xkp   = rpack + (size_t)NU * NU;

  hipLaunchKernelGGL(emb_to_bf16, dim3(25000), dim3(256), 0, stream, emb, embb);
  hipLaunchKernelGGL(pack_w, dim3(128), dim3(256), 0, stream, kernel_w, kpack);
  hipLaunchKernelGGL(pack_w, dim3(128), dim3(256), 0, stream, rec_w, rpack);
  hipLaunchKernelGGL(proj_gemm, dim3(1280), dim3(256), 0, stream, tokens, embb, kpack, bias, xkp);
  hipLaunchKernelGGL(rnn_rec, dim3(64), dim3(512), 0, stream, xkp, rpack, fcw, fcb, out);
}